// Round 3
// baseline (749.072 us; speedup 1.0000x reference)
//
#include <hip/hip_runtime.h>

typedef unsigned short u16;
typedef __attribute__((ext_vector_type(8))) unsigned short u16x8;
typedef __attribute__((ext_vector_type(8))) short s16x8;
typedef __attribute__((ext_vector_type(4))) float f32x4;

__device__ __forceinline__ float bf2f(u16 u){
  union { unsigned int i; float f; } v; v.i = ((unsigned int)u) << 16; return v.f;
}
__device__ __forceinline__ u16 f2bf(float f){
  union { float f; unsigned int i; } v; v.f = f;
  unsigned int r = v.i + 0x7fffu + ((v.i >> 16) & 1u);   // round-nearest-even
  return (u16)(r >> 16);
}

// ---------------------------------------------------------------------------
// Weight prep: dst[o][s*CIN+c] = bf16(src[o][c*5+s])   (K reorder + cast)
// ---------------------------------------------------------------------------
__global__ __launch_bounds__(256) void prep_w(
    const float* __restrict__ src, u16* __restrict__ dst, int CIN)
{
  const int KK = CIN * 5;
  const int i = blockIdx.x * 256 + threadIdx.x;
  if (i < 128 * KK) {
    const int o = i / KK, k = i % KK;
    const int s = k / CIN, c = k % CIN;
    dst[i] = f2bf(src[o * KK + c * 5 + s]);
  }
}

// ---------------------------------------------------------------------------
// K0: transpose fe [B,64,E] (fp32) -> feT [B,E,64] (bf16)
// ---------------------------------------------------------------------------
__global__ __launch_bounds__(256) void transpose64(
    const float* __restrict__ x, u16* __restrict__ xT, int E)
{
  __shared__ u16 tile[64][66];
  const int b   = blockIdx.z;
  const int e0  = blockIdx.x * 64;
  const int col = threadIdx.x & 63;
  const int r   = threadIdx.x >> 6;
  const int e   = e0 + col;
  #pragma unroll
  for (int k = 0; k < 16; k++) {
    const int c = r * 16 + k;
    float v = 0.f;
    if (e < E) v = x[((size_t)b * 64 + c) * (size_t)E + e];
    tile[c][col] = f2bf(v);
  }
  __syncthreads();
  const int e_l  = threadIdx.x >> 2;
  const int part = threadIdx.x & 3;
  const int eg   = e0 + e_l;
  if (eg < E) {
    u16* dst = xT + ((size_t)b * E + eg) * 64 + part * 16;
    #pragma unroll
    for (int h = 0; h < 2; h++) {
      u16x8 v;
      #pragma unroll
      for (int cc = 0; cc < 8; cc++) v[cc] = tile[part * 16 + h * 8 + cc][e_l];
      *(u16x8*)(dst + h * 8) = v;
    }
  }
}

// ---------------------------------------------------------------------------
// Conv, LDS-free: one wave = 16 edges x 128 outputs x full K.
// B-fragments gathered straight from xT [B,E,CIN] into registers:
//   k = s*CIN + c ; lane(lr,quad) holds edge e0+lr, channels quad*8..+8.
// Wp: [128][5*CIN] bf16 (K-reordered), bias fp32, y [B,128,E] fp32.
// ---------------------------------------------------------------------------
template <int CIN>
__global__ __launch_bounds__(256, 4) void conv_mfma(
    const u16* __restrict__ xT, const int* __restrict__ gidx,
    const u16* __restrict__ Wp, const float* __restrict__ bias,
    float* __restrict__ y, int E)
{
  constexpr int KK = CIN * 5;
  const int b    = blockIdx.z;
  const int t    = threadIdx.x;
  const int wv   = t >> 6, lane = t & 63;
  const int lr   = lane & 15, quad = lane >> 4;
  const size_t e0 = (size_t)blockIdx.x * 64 + wv * 16;
  size_t e_raw = e0 + lr;
  const int e = (int)(e_raw < (size_t)E ? e_raw : (size_t)(E - 1));

  const int4 g = *(const int4*)(gidx + ((size_t)b * E + e) * 4);
  const u16* base = xT + (size_t)b * E * CIN + quad * 8;
  const u16* r0 = base + (size_t)e   * CIN;
  const u16* r1 = base + (size_t)g.x * CIN;
  const u16* r2 = base + (size_t)g.y * CIN;
  const u16* r3 = base + (size_t)g.z * CIN;
  const u16* r4 = base + (size_t)g.w * CIN;

  f32x4 acc[8];
  #pragma unroll
  for (int i = 0; i < 8; i++) acc[i] = (f32x4){0.f, 0.f, 0.f, 0.f};

  #pragma unroll
  for (int ct = 0; ct < CIN / 32; ct++) {
    const int c0 = ct * 32;
    const u16x8 u0 = *(const u16x8*)(r0 + c0);
    const u16x8 u1 = *(const u16x8*)(r1 + c0);
    const u16x8 u2 = *(const u16x8*)(r2 + c0);
    const u16x8 u3 = *(const u16x8*)(r3 + c0);
    const u16x8 u4 = *(const u16x8*)(r4 + c0);
    u16x8 bfr[5];
    bfr[0] = u0;
    #pragma unroll
    for (int c = 0; c < 8; c++) {
      const float a1 = bf2f(u1[c]), a2 = bf2f(u2[c]);
      const float a3 = bf2f(u3[c]), a4 = bf2f(u4[c]);
      bfr[1][c] = f2bf(a1 + a3);
      bfr[2][c] = f2bf(a2 + a4);
      bfr[3][c] = f2bf(fabsf(a1 - a3));
      bfr[4][c] = f2bf(fabsf(a2 - a4));
    }
    #pragma unroll
    for (int s = 0; s < 5; s++) {
      const int kt = s * (CIN / 32) + ct;
      const s16x8 bb = (s16x8)bfr[s];
      const u16* wbase = Wp + (size_t)kt * 32 + quad * 8 + (size_t)lr * KK;
      #pragma unroll
      for (int mt = 0; mt < 8; mt++) {
        const s16x8 aa = *(const s16x8*)(wbase + (size_t)mt * 16 * KK);
        acc[mt] = __builtin_amdgcn_mfma_f32_16x16x32_bf16(aa, bb, acc[mt], 0, 0, 0);
      }
    }
  }

  // epilogue: D[row=quad*4+r][col=lr]
  if (e_raw < (size_t)E) {
    #pragma unroll
    for (int mt = 0; mt < 8; mt++) {
      #pragma unroll
      for (int r = 0; r < 4; r++) {
        const int m = mt * 16 + quad * 4 + r;
        y[((size_t)b * 128 + m) * E + e_raw] = acc[mt][r] + bias[m];
      }
    }
  }
}

// ---------------------------------------------------------------------------
// Row stats: one block per (b,o) row -> (mean, rsqrt(var+eps))
// ---------------------------------------------------------------------------
__global__ __launch_bounds__(256) void row_stats(
    const float* __restrict__ y, float2* __restrict__ stats, int E)
{
  const int row = blockIdx.x;
  const float* p = y + (size_t)row * E;
  float s = 0.f, s2 = 0.f;
  const int n4 = E >> 2;
  const float4* p4 = (const float4*)p;
  for (int i = threadIdx.x; i < n4; i += 256) {
    float4 v = p4[i];
    s  += v.x + v.y + v.z + v.w;
    s2 += v.x * v.x + v.y * v.y + v.z * v.z + v.w * v.w;
  }
  for (int i = n4 * 4 + threadIdx.x; i < E; i += 256) {
    float v = p[i]; s += v; s2 += v * v;
  }
  #pragma unroll
  for (int off = 32; off > 0; off >>= 1) {
    s  += __shfl_down(s, off);
    s2 += __shfl_down(s2, off);
  }
  __shared__ float rs[4], rs2[4];
  const int wv = threadIdx.x >> 6;
  if ((threadIdx.x & 63) == 0) { rs[wv] = s; rs2[wv] = s2; }
  __syncthreads();
  if (threadIdx.x == 0) {
    s = rs[0] + rs[1] + rs[2] + rs[3];
    s2 = rs2[0] + rs2[1] + rs2[2] + rs2[3];
    const float mean = s / E;
    const float var  = s2 / E - mean * mean;
    stats[row] = make_float2(mean, rsqrtf(var + 1e-5f));
  }
}

// ---------------------------------------------------------------------------
// Normalize + relu; write x1n [B,128,E] bf16 and transposed x1T [B,E,128] bf16
// ---------------------------------------------------------------------------
__global__ __launch_bounds__(256) void norm_relu_tr(
    const float* __restrict__ y, const float2* __restrict__ stats,
    u16* __restrict__ xn, u16* __restrict__ xT, int E)
{
  __shared__ u16 tile[32][66];
  const int b  = blockIdx.z;
  const int o0 = blockIdx.y * 32;
  const int e0 = blockIdx.x * 64;
  const int col = threadIdx.x & 63;
  const int r   = threadIdx.x >> 6;
  const int e   = e0 + col;
  #pragma unroll
  for (int k = 0; k < 8; k++) {
    const int ol = r * 8 + k;
    const int o  = o0 + ol;
    const float2 st = stats[b * 128 + o];
    float v = 0.f;
    if (e < E) v = y[((size_t)b * 128 + o) * E + e];
    float xv = (v - st.x) * st.y;
    if (xv < 0.f) xv = 0.f;
    const u16 u = f2bf(xv);
    if (e < E) xn[((size_t)b * 128 + o) * E + e] = u;
    tile[ol][col] = u;
  }
  __syncthreads();
  const int e_l  = threadIdx.x >> 2;
  const int part = threadIdx.x & 3;
  const int eg   = e0 + e_l;
  if (eg < E) {
    u16x8 v;
    #pragma unroll
    for (int cc = 0; cc < 8; cc++) v[cc] = tile[part * 8 + cc][e_l];
    *(u16x8*)(xT + ((size_t)b * E + eg) * 128 + o0 + part * 8) = v;
  }
}

// ---------------------------------------------------------------------------
// Final: out = relu( (y2 - m)*rstd + x1n ), fp32
// ---------------------------------------------------------------------------
__global__ __launch_bounds__(256) void final_k(
    const float* __restrict__ y, const float2* __restrict__ stats,
    const u16* __restrict__ xn, float* __restrict__ out, int E)
{
  const int b = blockIdx.z, o = blockIdx.y;
  const int e = blockIdx.x * 256 + threadIdx.x;
  if (e >= E) return;
  const float2 st = stats[b * 128 + o];
  const size_t idx = ((size_t)b * 128 + o) * E + e;
  float v = (y[idx] - st.x) * st.y + bf2f(xn[idx]);
  out[idx] = v < 0.f ? 0.f : v;
}

// ---------------------------------------------------------------------------
extern "C" void kernel_launch(void* const* d_in, const int* in_sizes, int n_in,
                              void* d_out, int out_size, void* d_ws, size_t ws_size,
                              hipStream_t stream)
{
  const float* fe  = (const float*)d_in[0];
  const int*   gmm = (const int*)d_in[1];
  const float* w1  = (const float*)d_in[2];
  const float* b1  = (const float*)d_in[3];
  const float* w2  = (const float*)d_in[4];
  const float* b2  = (const float*)d_in[5];
  float* out = (float*)d_out;

  const int B = 2, CIN = 64, COUT = 128;
  const int E = in_sizes[0] / (B * CIN);   // 100000

  // workspace layout (feT aliased with x1n: feT dead before x1n written)
  char* p = (char*)d_ws;
  auto alloc = [&](size_t bytes) -> char* {
    char* q = p; p += (bytes + 255) & ~(size_t)255; return q;
  };
  const size_t feT_b = (size_t)B * E * CIN * 2;
  const size_t x1n_b = (size_t)B * COUT * E * 2;
  char* regA = alloc(x1n_b > feT_b ? x1n_b : feT_b);
  u16*   feT = (u16*)regA;
  u16*   x1n = (u16*)regA;
  u16*   x1T = (u16*)alloc((size_t)B * E * COUT * 2);
  float* y   = (float*)alloc((size_t)B * COUT * E * 4);
  float2* stats = (float2*)alloc((size_t)B * COUT * sizeof(float2));
  u16* w1p = (u16*)alloc((size_t)COUT * CIN * 5 * 2);
  u16* w2p = (u16*)alloc((size_t)COUT * COUT * 5 * 2);

  const int n_w1 = COUT * CIN * 5, n_w2 = COUT * COUT * 5;
  prep_w <<<dim3((n_w1 + 255) / 256), 256, 0, stream>>>(w1, w1p, CIN);
  prep_w <<<dim3((n_w2 + 255) / 256), 256, 0, stream>>>(w2, w2p, COUT);

  transpose64 <<<dim3((E + 63) / 64, 1, B), 256, 0, stream>>>(fe, feT, E);
  conv_mfma<64> <<<dim3((E + 63) / 64, 1, B), 256, 0, stream>>>(feT, gmm, w1p, b1, y, E);
  row_stats <<<dim3(B * COUT), 256, 0, stream>>>(y, stats, E);
  norm_relu_tr <<<dim3((E + 63) / 64, COUT / 32, B), 256, 0, stream>>>(y, stats, x1n, x1T, E);
  conv_mfma<128> <<<dim3((E + 63) / 64, 1, B), 256, 0, stream>>>(x1T, gmm, w2p, b2, y, E);
  row_stats <<<dim3(B * COUT), 256, 0, stream>>>(y, stats, E);
  final_k <<<dim3((E + 255) / 256, COUT, B), 256, 0, stream>>>(y, stats, x1n, out, E);
}

// Round 4
// 622.766 us; speedup vs baseline: 1.2028x; 1.2028x over previous
//
#include <hip/hip_runtime.h>

typedef unsigned short u16;
typedef __attribute__((ext_vector_type(8))) unsigned short u16x8;
typedef __attribute__((ext_vector_type(8))) short s16x8;
typedef __attribute__((ext_vector_type(4))) float f32x4;

__device__ __forceinline__ float bf2f(u16 u){
  union { unsigned int i; float f; } v; v.i = ((unsigned int)u) << 16; return v.f;
}
__device__ __forceinline__ u16 f2bf(float f){
  union { float f; unsigned int i; } v; v.f = f;
  unsigned int r = v.i + 0x7fffu + ((v.i >> 16) & 1u);   // round-nearest-even
  return (u16)(r >> 16);
}

// ---------------------------------------------------------------------------
// Weight prep: dst[o][s*CIN+c] = bf16(src[o][c*5+s])   (K reorder + cast)
// ---------------------------------------------------------------------------
__global__ __launch_bounds__(256) void prep_w(
    const float* __restrict__ src, u16* __restrict__ dst, int CIN)
{
  const int KK = CIN * 5;
  const int i = blockIdx.x * 256 + threadIdx.x;
  if (i < 128 * KK) {
    const int o = i / KK, k = i % KK;
    const int s = k / CIN, c = k % CIN;
    dst[i] = f2bf(src[o * KK + c * 5 + s]);
  }
}

// ---------------------------------------------------------------------------
// zero both raw-stat buffers (ws is poisoned before every launch)
// ---------------------------------------------------------------------------
__global__ __launch_bounds__(256) void init_zero(
    float* __restrict__ a, float* __restrict__ b, int n)
{
  const int i = blockIdx.x * 256 + threadIdx.x;
  if (i < n) { a[i] = 0.f; b[i] = 0.f; }
}

// ---------------------------------------------------------------------------
// finalize: raw (sum, sumsq) per row -> (mean, rsqrt(var+eps))
// ---------------------------------------------------------------------------
__global__ __launch_bounds__(256) void stats_finalize(
    const float* __restrict__ raw, float2* __restrict__ stats, int nrows, float invE)
{
  const int i = blockIdx.x * 256 + threadIdx.x;
  if (i < nrows) {
    const float mean = raw[i * 2] * invE;
    const float var  = raw[i * 2 + 1] * invE - mean * mean;
    stats[i] = make_float2(mean, rsqrtf(var + 1e-5f));
  }
}

// ---------------------------------------------------------------------------
// K0: transpose fe [B,64,E] (fp32) -> feT [B,E,64] (bf16)
// ---------------------------------------------------------------------------
__global__ __launch_bounds__(256) void transpose64(
    const float* __restrict__ x, u16* __restrict__ xT, int E)
{
  __shared__ u16 tile[64][66];
  const int b   = blockIdx.z;
  const int e0  = blockIdx.x * 64;
  const int col = threadIdx.x & 63;
  const int r   = threadIdx.x >> 6;
  const int e   = e0 + col;
  #pragma unroll
  for (int k = 0; k < 16; k++) {
    const int c = r * 16 + k;
    float v = 0.f;
    if (e < E) v = x[((size_t)b * 64 + c) * (size_t)E + e];
    tile[c][col] = f2bf(v);
  }
  __syncthreads();
  const int e_l  = threadIdx.x >> 2;
  const int part = threadIdx.x & 3;
  const int eg   = e0 + e_l;
  if (eg < E) {
    u16* dst = xT + ((size_t)b * E + eg) * 64 + part * 16;
    #pragma unroll
    for (int h = 0; h < 2; h++) {
      u16x8 v;
      #pragma unroll
      for (int cc = 0; cc < 8; cc++) v[cc] = tile[part * 16 + h * 8 + cc][e_l];
      *(u16x8*)(dst + h * 8) = v;
    }
  }
}

// ---------------------------------------------------------------------------
// Persistent-wave conv + fused stats.
//   wave wv owns m in [wv*32, wv*32+32) (2 m-tiles); W A-frags live in VGPRs
//   (loaded ONCE). Grid-stride loop over 16-edge tiles; per tile: register
//   gather of 5 rows, feature build, 2*KT MFMA, store y, accumulate s/s2.
//   blockIdx.y = batch. No LDS, no barriers.
// ---------------------------------------------------------------------------
template <int CIN>
__global__ __launch_bounds__(256, 2) void conv_mfma(
    const u16* __restrict__ xT, const int* __restrict__ gidx,
    const u16* __restrict__ Wp, const float* __restrict__ bias,
    float* __restrict__ y, float* __restrict__ stats_raw, int E)
{
  constexpr int NC = CIN / 32;       // channel chunks of 32
  constexpr int KT = 5 * NC;         // K-tiles of 32
  constexpr int KK = CIN * 5;

  const int b    = blockIdx.y;
  const int t0   = blockIdx.x;
  const int lane = threadIdx.x & 63;
  const int wv   = threadIdx.x >> 6;
  const int lr   = lane & 15, quad = lane >> 4;

  // --- load W fragments into registers, once ---
  s16x8 aw[2][KT];
  #pragma unroll
  for (int i = 0; i < 2; i++) {
    const u16* wrow = Wp + (size_t)(wv * 32 + i * 16 + lr) * KK + quad * 8;
    #pragma unroll
    for (int kt = 0; kt < KT; kt++)
      aw[i][kt] = *(const s16x8*)(wrow + kt * 32);
  }
  // --- bias values for this lane's 8 output rows ---
  float bi[2][4];
  #pragma unroll
  for (int i = 0; i < 2; i++)
    #pragma unroll
    for (int r = 0; r < 4; r++)
      bi[i][r] = bias[wv * 32 + i * 16 + quad * 4 + r];

  float s1[2][4] = {{0,0,0,0},{0,0,0,0}};
  float s2[2][4] = {{0,0,0,0},{0,0,0,0}};

  const u16* base = xT + (size_t)b * E * CIN + quad * 8;
  const int ntiles = (E + 15) / 16;

  for (int t = t0; t < ntiles; t += gridDim.x) {
    const int e_raw = t * 16 + lr;
    const int e = e_raw < E ? e_raw : E - 1;
    const int4 g = *(const int4*)(gidx + ((size_t)b * E + e) * 4);
    const u16* r0 = base + (size_t)e   * CIN;
    const u16* r1 = base + (size_t)g.x * CIN;
    const u16* r2 = base + (size_t)g.y * CIN;
    const u16* r3 = base + (size_t)g.z * CIN;
    const u16* r4 = base + (size_t)g.w * CIN;

    f32x4 acc[2] = {{0.f,0.f,0.f,0.f},{0.f,0.f,0.f,0.f}};
    #pragma unroll
    for (int ct = 0; ct < NC; ct++) {
      const int c0 = ct * 32;
      const u16x8 u0 = *(const u16x8*)(r0 + c0);
      const u16x8 u1 = *(const u16x8*)(r1 + c0);
      const u16x8 u2 = *(const u16x8*)(r2 + c0);
      const u16x8 u3 = *(const u16x8*)(r3 + c0);
      const u16x8 u4 = *(const u16x8*)(r4 + c0);
      u16x8 bfr[5];
      bfr[0] = u0;
      #pragma unroll
      for (int c = 0; c < 8; c++) {
        const float a1 = bf2f(u1[c]), a2 = bf2f(u2[c]);
        const float a3 = bf2f(u3[c]), a4 = bf2f(u4[c]);
        bfr[1][c] = f2bf(a1 + a3);
        bfr[2][c] = f2bf(a2 + a4);
        bfr[3][c] = f2bf(fabsf(a1 - a3));
        bfr[4][c] = f2bf(fabsf(a2 - a4));
      }
      #pragma unroll
      for (int s = 0; s < 5; s++) {
        const int kt = s * NC + ct;
        const s16x8 bb = (s16x8)bfr[s];
        acc[0] = __builtin_amdgcn_mfma_f32_16x16x32_bf16(aw[0][kt], bb, acc[0], 0, 0, 0);
        acc[1] = __builtin_amdgcn_mfma_f32_16x16x32_bf16(aw[1][kt], bb, acc[1], 0, 0, 0);
      }
    }
    // epilogue: D[row=quad*4+r][col=lr]; add bias, store, accumulate stats
    if (e_raw < E) {
      #pragma unroll
      for (int i = 0; i < 2; i++) {
        #pragma unroll
        for (int r = 0; r < 4; r++) {
          const int m = wv * 32 + i * 16 + quad * 4 + r;
          const float v = acc[i][r] + bi[i][r];
          y[((size_t)b * 128 + m) * E + e_raw] = v;
          s1[i][r] += v;
          s2[i][r] += v * v;
        }
      }
    }
  }

  // --- wave-end stats flush: reduce over the 16 lr lanes, one atomic/row ---
  #pragma unroll
  for (int i = 0; i < 2; i++) {
    #pragma unroll
    for (int r = 0; r < 4; r++) {
      float sv = s1[i][r], qv = s2[i][r];
      #pragma unroll
      for (int off = 1; off < 16; off <<= 1) {
        sv += __shfl_xor(sv, off);
        qv += __shfl_xor(qv, off);
      }
      if (lr == 0) {
        const int m = wv * 32 + i * 16 + quad * 4 + r;
        atomicAdd(&stats_raw[(b * 128 + m) * 2 + 0], sv);
        atomicAdd(&stats_raw[(b * 128 + m) * 2 + 1], qv);
      }
    }
  }
}

// ---------------------------------------------------------------------------
// Normalize + relu; write x1n [B,128,E] bf16 and transposed x1T [B,E,128] bf16
// ---------------------------------------------------------------------------
__global__ __launch_bounds__(256) void norm_relu_tr(
    const float* __restrict__ y, const float2* __restrict__ stats,
    u16* __restrict__ xn, u16* __restrict__ xT, int E)
{
  __shared__ u16 tile[32][66];
  const int b  = blockIdx.z;
  const int o0 = blockIdx.y * 32;
  const int e0 = blockIdx.x * 64;
  const int col = threadIdx.x & 63;
  const int r   = threadIdx.x >> 6;
  const int e   = e0 + col;
  #pragma unroll
  for (int k = 0; k < 8; k++) {
    const int ol = r * 8 + k;
    const int o  = o0 + ol;
    const float2 st = stats[b * 128 + o];
    float v = 0.f;
    if (e < E) v = y[((size_t)b * 128 + o) * E + e];
    float xv = (v - st.x) * st.y;
    if (xv < 0.f) xv = 0.f;
    const u16 u = f2bf(xv);
    if (e < E) xn[((size_t)b * 128 + o) * E + e] = u;
    tile[ol][col] = u;
  }
  __syncthreads();
  const int e_l  = threadIdx.x >> 2;
  const int part = threadIdx.x & 3;
  const int eg   = e0 + e_l;
  if (eg < E) {
    u16x8 v;
    #pragma unroll
    for (int cc = 0; cc < 8; cc++) v[cc] = tile[part * 8 + cc][e_l];
    *(u16x8*)(xT + ((size_t)b * E + eg) * 128 + o0 + part * 8) = v;
  }
}

// ---------------------------------------------------------------------------
// Final: out = relu( (y2 - m)*rstd + x1n ), fp32
// ---------------------------------------------------------------------------
__global__ __launch_bounds__(256) void final_k(
    const float* __restrict__ y, const float2* __restrict__ stats,
    const u16* __restrict__ xn, float* __restrict__ out, int E)
{
  const int b = blockIdx.z, o = blockIdx.y;
  const int e = blockIdx.x * 256 + threadIdx.x;
  if (e >= E) return;
  const float2 st = stats[b * 128 + o];
  const size_t idx = ((size_t)b * 128 + o) * E + e;
  float v = (y[idx] - st.x) * st.y + bf2f(xn[idx]);
  out[idx] = v < 0.f ? 0.f : v;
}

// ---------------------------------------------------------------------------
extern "C" void kernel_launch(void* const* d_in, const int* in_sizes, int n_in,
                              void* d_out, int out_size, void* d_ws, size_t ws_size,
                              hipStream_t stream)
{
  const float* fe  = (const float*)d_in[0];
  const int*   gmm = (const int*)d_in[1];
  const float* w1  = (const float*)d_in[2];
  const float* b1  = (const float*)d_in[3];
  const float* w2  = (const float*)d_in[4];
  const float* b2  = (const float*)d_in[5];
  float* out = (float*)d_out;

  const int B = 2, CIN = 64, COUT = 128;
  const int E = in_sizes[0] / (B * CIN);   // 100000

  // workspace layout (feT aliased with x1n: feT dead before x1n written)
  char* p = (char*)d_ws;
  auto alloc = [&](size_t bytes) -> char* {
    char* q = p; p += (bytes + 255) & ~(size_t)255; return q;
  };
  const size_t feT_b = (size_t)B * E * CIN * 2;
  const size_t x1n_b = (size_t)B * COUT * E * 2;
  char* regA = alloc(x1n_b > feT_b ? x1n_b : feT_b);
  u16*   feT = (u16*)regA;
  u16*   x1n = (u16*)regA;
  u16*   x1T = (u16*)alloc((size_t)B * E * COUT * 2);
  float* y   = (float*)alloc((size_t)B * COUT * E * 4);
  float* raw1 = (float*)alloc((size_t)B * COUT * 2 * 4);
  float* raw2 = (float*)alloc((size_t)B * COUT * 2 * 4);
  float2* stats1 = (float2*)alloc((size_t)B * COUT * sizeof(float2));
  float2* stats2 = (float2*)alloc((size_t)B * COUT * sizeof(float2));
  u16* w1p = (u16*)alloc((size_t)COUT * CIN * 5 * 2);
  u16* w2p = (u16*)alloc((size_t)COUT * COUT * 5 * 2);

  const int n_w1 = COUT * CIN * 5, n_w2 = COUT * COUT * 5;
  const int nrows = B * COUT;
  const float invE = 1.f / (float)E;

  prep_w <<<dim3((n_w1 + 255) / 256), 256, 0, stream>>>(w1, w1p, CIN);
  prep_w <<<dim3((n_w2 + 255) / 256), 256, 0, stream>>>(w2, w2p, COUT);
  init_zero <<<dim3((nrows * 2 + 255) / 256), 256, 0, stream>>>(raw1, raw2, nrows * 2);

  transpose64 <<<dim3((E + 63) / 64, 1, B), 256, 0, stream>>>(fe, feT, E);
  conv_mfma<64> <<<dim3(384, B), 256, 0, stream>>>(feT, gmm, w1p, b1, y, raw1, E);
  stats_finalize <<<dim3((nrows + 255) / 256), 256, 0, stream>>>(raw1, stats1, nrows, invE);
  norm_relu_tr <<<dim3((E + 63) / 64, COUT / 32, B), 256, 0, stream>>>(y, stats1, x1n, x1T, E);
  conv_mfma<128> <<<dim3(256, B), 256, 0, stream>>>(x1T, gmm, w2p, b2, y, raw2, E);
  stats_finalize <<<dim3((nrows + 255) / 256), 256, 0, stream>>>(raw2, stats2, nrows, invE);
  final_k <<<dim3((E + 255) / 256, COUT, B), 256, 0, stream>>>(y, stats2, x1n, out, E);
}

// Round 5
// 552.376 us; speedup vs baseline: 1.3561x; 1.1274x over previous
//
#include <hip/hip_runtime.h>

typedef unsigned short u16;
typedef __attribute__((ext_vector_type(8))) unsigned short u16x8;
typedef __attribute__((ext_vector_type(8))) short s16x8;
typedef __attribute__((ext_vector_type(4))) float f32x4;
typedef __attribute__((ext_vector_type(4))) unsigned int u32x4;

__device__ __forceinline__ float bf2f(u16 u){
  union { unsigned int i; float f; } v; v.i = ((unsigned int)u) << 16; return v.f;
}
__device__ __forceinline__ u16 f2bf(float f){
  union { float f; unsigned int i; } v; v.f = f;
  unsigned int r = v.i + 0x7fffu + ((v.i >> 16) & 1u);
  return (u16)(r >> 16);
}
// pack2(a,b) -> u32 = (bf16(b)<<16) | bf16(a), round-nearest (ties up): 3 VALU
__device__ __forceinline__ unsigned int pack2(float a, float b){
  union { float f; unsigned int i; } x, y; x.f = a; y.f = b;
  return __builtin_amdgcn_perm(y.i + 0x8000u, x.i + 0x8000u, 0x07060302u);
}

// ---------------------------------------------------------------------------
// Weight prep: dst[o][s*CIN+c] = bf16(src[o][c*5+s])   (K reorder + cast)
// ---------------------------------------------------------------------------
__global__ __launch_bounds__(256) void prep_w(
    const float* __restrict__ src, u16* __restrict__ dst, int CIN)
{
  const int KK = CIN * 5;
  const int i = blockIdx.x * 256 + threadIdx.x;
  if (i < 128 * KK) {
    const int o = i / KK, k = i % KK;
    const int s = k / CIN, c = k % CIN;
    dst[i] = f2bf(src[o * KK + c * 5 + s]);
  }
}

__global__ __launch_bounds__(256) void init_zero(
    float* __restrict__ a, float* __restrict__ b, int n)
{
  const int i = blockIdx.x * 256 + threadIdx.x;
  if (i < n) { a[i] = 0.f; b[i] = 0.f; }
}

__global__ __launch_bounds__(256) void stats_finalize(
    const float* __restrict__ raw, float2* __restrict__ stats, int nrows, float invE)
{
  const int i = blockIdx.x * 256 + threadIdx.x;
  if (i < nrows) {
    const float mean = raw[i * 2] * invE;
    const float var  = raw[i * 2 + 1] * invE - mean * mean;
    stats[i] = make_float2(mean, rsqrtf(var + 1e-5f));
  }
}

// ---------------------------------------------------------------------------
// transpose fe [B,64,E] (fp32) -> feT [B,E,64] (bf16)
// ---------------------------------------------------------------------------
__global__ __launch_bounds__(256) void transpose64(
    const float* __restrict__ x, u16* __restrict__ xT, int E)
{
  __shared__ u16 tile[64][66];
  const int b   = blockIdx.z;
  const int e0  = blockIdx.x * 64;
  const int col = threadIdx.x & 63;
  const int r   = threadIdx.x >> 6;
  const int e   = e0 + col;
  #pragma unroll
  for (int k = 0; k < 16; k++) {
    const int c = r * 16 + k;
    float v = 0.f;
    if (e < E) v = x[((size_t)b * 64 + c) * (size_t)E + e];
    tile[c][col] = f2bf(v);
  }
  __syncthreads();
  const int e_l  = threadIdx.x >> 2;
  const int part = threadIdx.x & 3;
  const int eg   = e0 + e_l;
  if (eg < E) {
    u16* dst = xT + ((size_t)b * E + eg) * 64 + part * 16;
    #pragma unroll
    for (int h = 0; h < 2; h++) {
      u16x8 v;
      #pragma unroll
      for (int cc = 0; cc < 8; cc++) v[cc] = tile[part * 16 + h * 8 + cc][e_l];
      *(u16x8*)(dst + h * 8) = v;
    }
  }
}

// ---------------------------------------------------------------------------
// Persistent-wave conv, software-pipelined, y stored bf16 edge-major [B,E,128].
// Wave owns m in [wv*32,+32); W frags resident. Tile = 16 edges.
// ---------------------------------------------------------------------------
template <int CIN>
__global__ __launch_bounds__(256, 2) void conv_mfma(
    const u16* __restrict__ xT, const int* __restrict__ gidx,
    const u16* __restrict__ Wp, const float* __restrict__ bias,
    u16* __restrict__ yT, float* __restrict__ statsr, int E)
{
  constexpr int NC = CIN / 32, KT = 5 * NC, KK = CIN * 5, CB = CIN * 2;
  const int b    = blockIdx.y;
  const int lane = threadIdx.x & 63, wv = threadIdx.x >> 6;
  const int lr   = lane & 15, quad = lane >> 4;

  s16x8 aw[2][KT];
  #pragma unroll
  for (int i = 0; i < 2; i++) {
    const u16* wr = Wp + (size_t)(wv * 32 + i * 16 + lr) * KK + quad * 8;
    #pragma unroll
    for (int kt = 0; kt < KT; kt++) aw[i][kt] = *(const s16x8*)(wr + kt * 32);
  }

  float s1[8] = {0,0,0,0,0,0,0,0}, s2[8] = {0,0,0,0,0,0,0,0};
  const char* base  = (const char*)xT + (size_t)b * E * CB + quad * 16;
  const int*  gbase = gidx + (size_t)b * E * 4;
  u16* ybase = yT + (size_t)b * E * 128 + wv * 32 + quad * 4;
  const float* bbase = bias + wv * 32 + quad * 4;

  const int ntiles = (E + 15) >> 4, gs = gridDim.x;

  auto LDG = [&](int t) -> int4 {
    int e = t * 16 + lr; if (e >= E) e = E - 1;
    return *(const int4*)(gbase + (size_t)e * 4);
  };
  auto MKOFF = [&](int t, int4 g, unsigned int* o) {
    int e = t * 16 + lr; if (e >= E) e = E - 1;
    o[0] = (unsigned int)e * CB;   o[1] = (unsigned int)g.x * CB;
    o[2] = (unsigned int)g.y * CB; o[3] = (unsigned int)g.z * CB;
    o[4] = (unsigned int)g.w * CB;
  };
  auto LDCH = [&](const unsigned int* o, int ct, u16x8* d) {
    const int cb = ct * 64;
    #pragma unroll
    for (int j = 0; j < 5; j++) d[j] = *(const u16x8*)(base + o[j] + cb);
  };
  auto BUILD = [&](const u16x8* u, s16x8* bb) {
    bb[0] = (s16x8)u[0];
    u32x4 o1, o2, o3, o4;
    #pragma unroll
    for (int p = 0; p < 4; p++) {
      const int c = 2 * p;
      float a1e = bf2f(u[1][c]), a1o = bf2f(u[1][c+1]);
      float a2e = bf2f(u[2][c]), a2o = bf2f(u[2][c+1]);
      float a3e = bf2f(u[3][c]), a3o = bf2f(u[3][c+1]);
      float a4e = bf2f(u[4][c]), a4o = bf2f(u[4][c+1]);
      o1[p] = pack2(a1e + a3e, a1o + a3o);
      o2[p] = pack2(a2e + a4e, a2o + a4o);
      o3[p] = pack2(fabsf(a1e - a3e), fabsf(a1o - a3o));
      o4[p] = pack2(fabsf(a2e - a4e), fabsf(a2o - a4o));
    }
    bb[1] = __builtin_bit_cast(s16x8, o1);
    bb[2] = __builtin_bit_cast(s16x8, o2);
    bb[3] = __builtin_bit_cast(s16x8, o3);
    bb[4] = __builtin_bit_cast(s16x8, o4);
  };
  auto MFMA = [&](int ct, const s16x8* bb, f32x4* acc) {
    #pragma unroll
    for (int s = 0; s < 5; s++) {
      acc[0] = __builtin_amdgcn_mfma_f32_16x16x32_bf16(aw[0][s*NC+ct], bb[s], acc[0], 0, 0, 0);
      acc[1] = __builtin_amdgcn_mfma_f32_16x16x32_bf16(aw[1][s*NC+ct], bb[s], acc[1], 0, 0, 0);
    }
  };
  auto EPI = [&](int t, const f32x4* acc) {
    const int er = t * 16 + lr;
    if (er < E) {
      u16* yrow = ybase + (size_t)er * 128;
      #pragma unroll
      for (int i = 0; i < 2; i++) {
        const float4 bv = *(const float4*)(bbase + i * 16);
        const float v0 = acc[i][0] + bv.x, v1 = acc[i][1] + bv.y;
        const float v2 = acc[i][2] + bv.z, v3 = acc[i][3] + bv.w;
        s1[i*4+0] += v0; s2[i*4+0] += v0 * v0;
        s1[i*4+1] += v1; s2[i*4+1] += v1 * v1;
        s1[i*4+2] += v2; s2[i*4+2] += v2 * v2;
        s1[i*4+3] += v3; s2[i*4+3] += v3 * v3;
        uint2 pk; pk.x = pack2(v0, v1); pk.y = pack2(v2, v3);
        *(uint2*)(yrow + i * 16) = pk;
      }
    }
  };

  if constexpr (NC == 4) {
    // ---- conv2: single-tile iteration, 2-slot chunk pipeline ----
    int t = blockIdx.x;
    int4 g = LDG(t);
    unsigned int off[5]; MKOFF(t, g, off);
    u16x8 A[5], Bf[5];
    LDCH(off, 0, A); LDCH(off, 1, Bf);
    int4 gn = LDG(t + gs);
    for (; t < ntiles; t += gs) {
      f32x4 acc[2] = {{0.f,0.f,0.f,0.f},{0.f,0.f,0.f,0.f}};
      s16x8 bb[5];
      BUILD(A, bb);  LDCH(off, 2, A);  MFMA(0, bb, acc);
      BUILD(Bf, bb); LDCH(off, 3, Bf); MFMA(1, bb, acc);
      unsigned int offn[5]; MKOFF(t + gs, gn, offn);
      int4 gn2 = LDG(t + 2 * gs);
      BUILD(A, bb);  LDCH(offn, 0, A);  MFMA(2, bb, acc);
      BUILD(Bf, bb); LDCH(offn, 1, Bf); MFMA(3, bb, acc);
      EPI(t, acc);
      #pragma unroll
      for (int j = 0; j < 5; j++) off[j] = offn[j];
      gn = gn2;
    }
  } else {
    // ---- conv1: two-tile iteration, 4-slot ring (deep pipeline) ----
    int t = blockIdx.x;
    int4 gA = LDG(t), gB = LDG(t + gs);
    unsigned int offA[5], offB[5];
    MKOFF(t, gA, offA); MKOFF(t + gs, gB, offB);
    u16x8 A[5], B2[5], C[5], D[5];
    LDCH(offA, 0, A); LDCH(offA, 1, B2);
    LDCH(offB, 0, C); LDCH(offB, 1, D);
    gA = LDG(t + 2 * gs); gB = LDG(t + 3 * gs);
    for (; t < ntiles; t += 2 * gs) {
      s16x8 bb[5];
      {
        f32x4 acc[2] = {{0.f,0.f,0.f,0.f},{0.f,0.f,0.f,0.f}};
        unsigned int offn[5]; MKOFF(t + 2 * gs, gA, offn);
        int4 g2 = LDG(t + 4 * gs);
        BUILD(A, bb);  LDCH(offn, 0, A);  MFMA(0, bb, acc);
        BUILD(B2, bb); LDCH(offn, 1, B2); MFMA(1, bb, acc);
        EPI(t, acc);
        #pragma unroll
        for (int j = 0; j < 5; j++) offA[j] = offn[j];
        gA = g2;
      }
      {
        f32x4 acc[2] = {{0.f,0.f,0.f,0.f},{0.f,0.f,0.f,0.f}};
        unsigned int offn[5]; MKOFF(t + 3 * gs, gB, offn);
        int4 g2 = LDG(t + 5 * gs);
        BUILD(C, bb); LDCH(offn, 0, C); MFMA(0, bb, acc);
        BUILD(D, bb); LDCH(offn, 1, D); MFMA(1, bb, acc);
        EPI(t + gs, acc);
        #pragma unroll
        for (int j = 0; j < 5; j++) offB[j] = offn[j];
        gB = g2;
      }
    }
  }

  // stats flush: reduce over 16 edge-lanes, one atomic per row
  #pragma unroll
  for (int i = 0; i < 2; i++) {
    #pragma unroll
    for (int r = 0; r < 4; r++) {
      float sv = s1[i*4+r], qv = s2[i*4+r];
      #pragma unroll
      for (int off = 1; off < 16; off <<= 1) {
        sv += __shfl_xor(sv, off);
        qv += __shfl_xor(qv, off);
      }
      if (lr == 0) {
        const int m = wv * 32 + i * 16 + quad * 4 + r;
        atomicAdd(&statsr[(b * 128 + m) * 2 + 0], sv);
        atomicAdd(&statsr[(b * 128 + m) * 2 + 1], qv);
      }
    }
  }
}

// ---------------------------------------------------------------------------
// Element-wise norm+relu in edge-major: x1T[e,c] = relu((y1T[e,c]-m_c)*r_c)
// ---------------------------------------------------------------------------
__global__ __launch_bounds__(256) void norm_et(
    const u16* __restrict__ yT, const float2* __restrict__ st,
    u16* __restrict__ xT, int E)
{
  const int b  = blockIdx.y;
  const int c0 = (threadIdx.x & 15) * 8;
  float2 s[8];
  #pragma unroll
  for (int k = 0; k < 8; k++) s[k] = st[b * 128 + c0 + k];
  const size_t base = (size_t)b * E * 128;
  for (int e = blockIdx.x * 16 + (threadIdx.x >> 4); e < E; e += gridDim.x * 16) {
    const u16x8 u = *(const u16x8*)(yT + base + (size_t)e * 128 + c0);
    u32x4 o;
    #pragma unroll
    for (int p = 0; p < 4; p++) {
      float xe = (bf2f(u[2*p])   - s[2*p].x)   * s[2*p].y;
      float xo = (bf2f(u[2*p+1]) - s[2*p+1].x) * s[2*p+1].y;
      xe = xe < 0.f ? 0.f : xe;
      xo = xo < 0.f ? 0.f : xo;
      o[p] = pack2(xe, xo);
    }
    *(u32x4*)(xT + base + (size_t)e * 128 + c0) = o;
  }
}

// ---------------------------------------------------------------------------
// Final: out[b,c,e] = relu( norm2(y2T) + relu(norm1(y1T)) ), LDS-transposed
// ---------------------------------------------------------------------------
__global__ __launch_bounds__(256) void final_k(
    const u16* __restrict__ y1T, const u16* __restrict__ y2T,
    const float2* __restrict__ st1, const float2* __restrict__ st2,
    float* __restrict__ out, int E)
{
  __shared__ float tile[128][65];
  const int b  = blockIdx.y;
  const int e0 = blockIdx.x * 64;
  const int c0 = (threadIdx.x & 15) * 8;
  const int eo = threadIdx.x >> 4;
  float2 a1[8], a2[8];
  #pragma unroll
  for (int k = 0; k < 8; k++) {
    a1[k] = st1[b * 128 + c0 + k];
    a2[k] = st2[b * 128 + c0 + k];
  }
  #pragma unroll
  for (int p = 0; p < 4; p++) {
    int e = e0 + p * 16 + eo;
    int ec = e < E ? e : E - 1;
    const u16x8 u1 = *(const u16x8*)(y1T + ((size_t)b * E + ec) * 128 + c0);
    const u16x8 u2 = *(const u16x8*)(y2T + ((size_t)b * E + ec) * 128 + c0);
    #pragma unroll
    for (int k = 0; k < 8; k++) {
      float x1 = (bf2f(u1[k]) - a1[k].x) * a1[k].y;
      x1 = x1 < 0.f ? 0.f : x1;
      float v = (bf2f(u2[k]) - a2[k].x) * a2[k].y + x1;
      v = v < 0.f ? 0.f : v;
      tile[c0 + k][p * 16 + eo] = v;
    }
  }
  __syncthreads();
  const int el = threadIdx.x & 63, ch0 = threadIdx.x >> 6;
  const int e  = e0 + el;
  if (e < E) {
    #pragma unroll
    for (int j = 0; j < 32; j++) {
      const int c = j * 4 + ch0;
      out[((size_t)b * 128 + c) * E + e] = tile[c][el];
    }
  }
}

// ---------------------------------------------------------------------------
extern "C" void kernel_launch(void* const* d_in, const int* in_sizes, int n_in,
                              void* d_out, int out_size, void* d_ws, size_t ws_size,
                              hipStream_t stream)
{
  const float* fe  = (const float*)d_in[0];
  const int*   gmm = (const int*)d_in[1];
  const float* w1  = (const float*)d_in[2];
  const float* b1  = (const float*)d_in[3];
  const float* w2  = (const float*)d_in[4];
  const float* b2  = (const float*)d_in[5];
  float* out = (float*)d_out;

  const int B = 2, CIN = 64, COUT = 128;
  const int E = in_sizes[0] / (B * CIN);   // 100000

  char* p = (char*)d_ws;
  auto alloc = [&](size_t bytes) -> char* {
    char* q = p; p += (bytes + 255) & ~(size_t)255; return q;
  };
  u16*   feT = (u16*)alloc((size_t)B * E * CIN * 2);
  u16*   y1T = (u16*)alloc((size_t)B * E * COUT * 2);
  u16*   x1T = (u16*)alloc((size_t)B * E * COUT * 2);
  u16*   y2T = (u16*)alloc((size_t)B * E * COUT * 2);
  float* raw1 = (float*)alloc((size_t)B * COUT * 2 * 4);
  float* raw2 = (float*)alloc((size_t)B * COUT * 2 * 4);
  float2* stats1 = (float2*)alloc((size_t)B * COUT * sizeof(float2));
  float2* stats2 = (float2*)alloc((size_t)B * COUT * sizeof(float2));
  u16* w1p = (u16*)alloc((size_t)COUT * CIN * 5 * 2);
  u16* w2p = (u16*)alloc((size_t)COUT * COUT * 5 * 2);

  const int n_w1 = COUT * CIN * 5, n_w2 = COUT * COUT * 5;
  const int nrows = B * COUT;
  const float invE = 1.f / (float)E;

  prep_w <<<dim3((n_w1 + 255) / 256), 256, 0, stream>>>(w1, w1p, CIN);
  prep_w <<<dim3((n_w2 + 255) / 256), 256, 0, stream>>>(w2, w2p, COUT);
  init_zero <<<dim3((nrows * 2 + 255) / 256), 256, 0, stream>>>(raw1, raw2, nrows * 2);

  transpose64 <<<dim3((E + 63) / 64, 1, B), 256, 0, stream>>>(fe, feT, E);
  conv_mfma<64> <<<dim3(256, B), 256, 0, stream>>>(feT, gmm, w1p, b1, y1T, raw1, E);
  stats_finalize <<<dim3((nrows + 255) / 256), 256, 0, stream>>>(raw1, stats1, nrows, invE);
  norm_et <<<dim3(512, B), 256, 0, stream>>>(y1T, stats1, x1T, E);
  conv_mfma<128> <<<dim3(256, B), 256, 0, stream>>>(x1T, gmm, w2p, b2, y2T, raw2, E);
  stats_finalize <<<dim3((nrows + 255) / 256), 256, 0, stream>>>(raw2, stats2, nrows, invE);
  final_k <<<dim3((E + 63) / 64, B), 256, 0, stream>>>(y1T, y2T, stats1, stats2, out, E);
}